// Round 4
// baseline (887.713 us; speedup 1.0000x reference)
//
#include <hip/hip_runtime.h>
#include <math.h>

constexpr int NN  = 50000;   // nodes
constexpr int NE  = 800000;  // edges
constexpr int IND = 128;     // input dim
constexpr int HCD = 128;     // heads*channels
constexpr float NEG_SLOPE = 0.2f;

typedef __attribute__((ext_vector_type(8))) short bf16x8;
typedef __attribute__((ext_vector_type(4))) float f32x4;

// split fp32 -> bf16 hi + bf16 lo (truncation; lo catches the residual).
__device__ __forceinline__ void splitbf(float f, unsigned short &h, unsigned short &lo) {
    unsigned u = __float_as_uint(f);
    h = (unsigned short)(u >> 16);
    float fh = __uint_as_float(u & 0xffff0000u);
    lo = (unsigned short)(__float_as_uint(f - fh) >> 16);
}

// ---------------------------------------------------------------------------
// K1: MFMA split-bf16 GEMM (grid.y: 0 -> xl = x@Wl+bl, 1 -> xr = x@Wr+br)
// ---------------------------------------------------------------------------
constexpr int BM = 128;
constexpr int BK = 64;

__global__ __launch_bounds__(256) void gemm_mfma(
    const float* __restrict__ x, const float* __restrict__ Wl,
    const float* __restrict__ Wr, const float* __restrict__ bl,
    const float* __restrict__ br, float* __restrict__ xl, float* __restrict__ xr)
{
    extern __shared__ char smem[];      // 64 KB
    char* Ah = smem;                    // [128][64] bf16
    char* Al = smem + 16384;
    char* Bh = smem + 32768;            // [c=128][k=64] bf16 (W transposed)
    char* Bl = smem + 49152;

    const int tid = threadIdx.x;
    const float* W  = blockIdx.y ? Wr : Wl;
    const float* bv = blockIdx.y ? br : bl;
    float* outp     = blockIdx.y ? xr : xl;
    const int bn = blockIdx.x * BM;

    const int l   = tid & 63;
    const int wid = tid >> 6;
    const int wr  = (wid >> 1) * 64;
    const int wc  = (wid & 1) * 64;
    const int lr  = l & 15;
    const int kg  = l >> 4;

    f32x4 acc[4][4];
#pragma unroll
    for (int s = 0; s < 4; ++s)
#pragma unroll
        for (int f = 0; f < 4; ++f) acc[s][f] = (f32x4){0.f, 0.f, 0.f, 0.f};

    const int cB  = tid & 127;
    const int khB = tid >> 7;

    for (int ki = 0; ki < 2; ++ki) {
#pragma unroll
        for (int r = 0; r < 8; ++r) {
            int g = tid + r * 256;
            int row = g >> 4, k4 = g & 15;
            int node = bn + row;
            float4 v = make_float4(0.f, 0.f, 0.f, 0.f);
            if (node < NN) v = *(const float4*)&x[node * IND + ki * BK + k4 * 4];
            unsigned short h0, h1, h2, h3, q0, q1, q2, q3;
            splitbf(v.x, h0, q0); splitbf(v.y, h1, q1);
            splitbf(v.z, h2, q2); splitbf(v.w, h3, q3);
            int off = (row * BK + k4 * 4) * 2;
            int swz = off ^ ((row & 7) << 4);
            *(ushort4*)(Ah + swz) = make_ushort4(h0, h1, h2, h3);
            *(ushort4*)(Al + swz) = make_ushort4(q0, q1, q2, q3);
        }
#pragma unroll
        for (int r = 0; r < 8; ++r) {
            int kb = r * 8 + khB * 4;
            float f0 = W[(ki * BK + kb + 0) * HCD + cB];
            float f1 = W[(ki * BK + kb + 1) * HCD + cB];
            float f2 = W[(ki * BK + kb + 2) * HCD + cB];
            float f3 = W[(ki * BK + kb + 3) * HCD + cB];
            unsigned short h0, h1, h2, h3, q0, q1, q2, q3;
            splitbf(f0, h0, q0); splitbf(f1, h1, q1);
            splitbf(f2, h2, q2); splitbf(f3, h3, q3);
            int off = (cB * BK + kb) * 2;
            int swz = off ^ ((cB & 7) << 4);
            *(ushort4*)(Bh + swz) = make_ushort4(h0, h1, h2, h3);
            *(ushort4*)(Bl + swz) = make_ushort4(q0, q1, q2, q3);
        }
        __syncthreads();
#pragma unroll
        for (int kk = 0; kk < 2; ++kk) {
            bf16x8 Bfh[4], Bfl[4];
#pragma unroll
            for (int f = 0; f < 4; ++f) {
                int c = wc + f * 16 + lr;
                int swz = (c * 128 + kk * 64 + kg * 16) ^ ((c & 7) << 4);
                Bfh[f] = *(const bf16x8*)(Bh + swz);
                Bfl[f] = *(const bf16x8*)(Bl + swz);
            }
#pragma unroll
            for (int s = 0; s < 4; ++s) {
                int row = wr + s * 16 + lr;
                int swz = (row * 128 + kk * 64 + kg * 16) ^ ((row & 7) << 4);
                bf16x8 Afh = *(const bf16x8*)(Ah + swz);
                bf16x8 Afl = *(const bf16x8*)(Al + swz);
#pragma unroll
                for (int f = 0; f < 4; ++f) {
                    acc[s][f] = __builtin_amdgcn_mfma_f32_16x16x32_bf16(Afh, Bfh[f], acc[s][f], 0, 0, 0);
                    acc[s][f] = __builtin_amdgcn_mfma_f32_16x16x32_bf16(Afh, Bfl[f], acc[s][f], 0, 0, 0);
                    acc[s][f] = __builtin_amdgcn_mfma_f32_16x16x32_bf16(Afl, Bfh[f], acc[s][f], 0, 0, 0);
                }
            }
        }
        __syncthreads();
    }
#pragma unroll
    for (int s = 0; s < 4; ++s)
#pragma unroll
        for (int f = 0; f < 4; ++f) {
            int c = wc + f * 16 + lr;
            float bb = bv[c];
#pragma unroll
            for (int j = 0; j < 4; ++j) {
                int r = bn + wr + s * 16 + kg * 4 + j;
                if (r < NN) outp[r * HCD + c] = acc[s][f][j] + bb;
            }
        }
}

// ---------------------------------------------------------------------------
// K2: in-degree count
// ---------------------------------------------------------------------------
__global__ __launch_bounds__(256) void deg_kernel(const int* __restrict__ dst,
                                                  int* __restrict__ deg)
{
    int e = blockIdx.x * 256 + threadIdx.x;
    if (e < NE) atomicAdd(&deg[dst[e]], 1);
}

// ---------------------------------------------------------------------------
// K3a/b/c: 3-phase coalesced exclusive scan of deg -> off
// ---------------------------------------------------------------------------
constexpr int SB = (NN + 255) / 256;   // 196 scan blocks

__global__ __launch_bounds__(256) void scan1(const int* __restrict__ deg,
                                             int* __restrict__ bsum)
{
    __shared__ int red[4];
    int idx = blockIdx.x * 256 + threadIdx.x;
    int v = (idx < NN) ? deg[idx] : 0;
    for (int d = 32; d; d >>= 1) v += __shfl_down(v, d);
    if ((threadIdx.x & 63) == 0) red[threadIdx.x >> 6] = v;
    __syncthreads();
    if (threadIdx.x == 0) bsum[blockIdx.x] = red[0] + red[1] + red[2] + red[3];
}

__global__ __launch_bounds__(256) void scan2(const int* __restrict__ bsum,
                                             int* __restrict__ boff)
{
    __shared__ int t[256];
    int tid = threadIdx.x;
    int v = (tid < SB) ? bsum[tid] : 0;
    t[tid] = v;
    __syncthreads();
    for (int d = 1; d < 256; d <<= 1) {
        int u = (tid >= d) ? t[tid - d] : 0;
        __syncthreads();
        t[tid] += u;
        __syncthreads();
    }
    boff[tid] = t[tid] - v;
}

__global__ __launch_bounds__(256) void scan3(const int* __restrict__ deg,
                                             const int* __restrict__ boff,
                                             int* __restrict__ off)
{
    __shared__ int t[256];
    int tid = threadIdx.x;
    int idx = blockIdx.x * 256 + tid;
    int v = (idx < NN) ? deg[idx] : 0;
    t[tid] = v;
    __syncthreads();
    for (int d = 1; d < 256; d <<= 1) {
        int u = (tid >= d) ? t[tid - d] : 0;
        __syncthreads();
        t[tid] += u;
        __syncthreads();
    }
    int excl = t[tid] - v + boff[blockIdx.x];
    if (idx < NN) off[idx] = excl;
    if (idx == NN - 1) off[NN] = excl + v;
}

// ---------------------------------------------------------------------------
// K4: CSR fill — packed (src, ea) int2, single 8B store per edge
// ---------------------------------------------------------------------------
__global__ __launch_bounds__(256) void fill_kernel(
    const int* __restrict__ src, const int* __restrict__ dst,
    const float* __restrict__ ea, const int* __restrict__ off,
    int* __restrict__ cursor, int2* __restrict__ csr)
{
    int e = blockIdx.x * 256 + threadIdx.x;
    if (e >= NE) return;
    int d = dst[e];
    int pos = atomicAdd(&cursor[d], 1);
    csr[off[d] + pos] = make_int2(src[e], __float_as_int(ea[e]));
}

// ---------------------------------------------------------------------------
// K5: persistent-wave node kernel. Each wave pops node ids from a global
// queue (perfect load balance, full residency). Per node: 4-edge unroll,
// 4-deep prefetch, defer-max online softmax, aggregation.
// Lane l owns channels 2l,2l+1 (head = l>>4). bias omitted (cancels in BN).
// ---------------------------------------------------------------------------
__global__ __launch_bounds__(256) void node_kernel(
    const float* __restrict__ xl, const float* __restrict__ xr,
    const float* __restrict__ We, const float* __restrict__ att,
    const int* __restrict__ off, const int2* __restrict__ csr,
    int* __restrict__ wq, float* __restrict__ out_pre)
{
    const int l  = threadIdx.x & 63;
    const int c0 = l * 2;
    const float2 wev = *(const float2*)&We[c0];
    const float2 atv = *(const float2*)&att[c0];

    for (;;) {
        int n = 0;
        if (l == 0) n = atomicAdd(wq, 1);
        n = __shfl(n, 0);
        if (n >= NN) return;

        const float2 xrv = *(const float2*)&xr[n * HCD + c0];
        const int s = off[n], e = off[n + 1];

        float mx = -3.402823466e38f, sm = 0.f, a0 = 0.f, a1 = 0.f;

        auto score = [&](float2 xlv, float eav) -> float {
            float m0 = xlv.x + xrv.x + eav * wev.x;
            float m1 = xlv.y + xrv.y + eav * wev.y;
            m0 = (m0 > 0.f) ? m0 : NEG_SLOPE * m0;
            m1 = (m1 > 0.f) ? m1 : NEG_SLOPE * m1;
            float p = m0 * atv.x + m1 * atv.y;
            p += __shfl_xor(p, 8);
            p += __shfl_xor(p, 4);
            p += __shfl_xor(p, 2);
            p += __shfl_xor(p, 1);
            return p;
        };
        auto one = [&](float p, float2 xv) {
            if (p > mx + 8.f) {
                float sc = __expf(mx - p);
                sm *= sc; a0 *= sc; a1 *= sc; mx = p;
            }
            float ev = __expf(p - mx);
            sm += ev;
            a0 = fmaf(ev, xv.x, a0);
            a1 = fmaf(ev, xv.y, a1);
        };

        int k = s;
        int2 cA, cB, cC, cD; float2 xA, xB, xC, xD;
        if (k     < e) { cA = csr[k];     xA = *(const float2*)&xl[cA.x * HCD + c0]; }
        if (k + 1 < e) { cB = csr[k + 1]; xB = *(const float2*)&xl[cB.x * HCD + c0]; }
        if (k + 2 < e) { cC = csr[k + 2]; xC = *(const float2*)&xl[cC.x * HCD + c0]; }
        if (k + 3 < e) { cD = csr[k + 3]; xD = *(const float2*)&xl[cD.x * HCD + c0]; }

        for (; k + 4 <= e; k += 4) {
            int2 cE, cF, cG, cH; float2 xE, xF, xG, xH;
            if (k + 4 < e) { cE = csr[k + 4]; xE = *(const float2*)&xl[cE.x * HCD + c0]; }
            if (k + 5 < e) { cF = csr[k + 5]; xF = *(const float2*)&xl[cF.x * HCD + c0]; }
            if (k + 6 < e) { cG = csr[k + 6]; xG = *(const float2*)&xl[cG.x * HCD + c0]; }
            if (k + 7 < e) { cH = csr[k + 7]; xH = *(const float2*)&xl[cH.x * HCD + c0]; }

            float pA = score(xA, __int_as_float(cA.y));
            float pB = score(xB, __int_as_float(cB.y));
            float pC = score(xC, __int_as_float(cC.y));
            float pD = score(xD, __int_as_float(cD.y));
            float pm = fmaxf(fmaxf(pA, pB), fmaxf(pC, pD));
            if (pm > mx + 8.f) {                  // rare rescale (per head group)
                float sc = __expf(mx - pm);
                sm *= sc; a0 *= sc; a1 *= sc; mx = pm;
            }
            float evA = __expf(pA - mx);
            float evB = __expf(pB - mx);
            float evC = __expf(pC - mx);
            float evD = __expf(pD - mx);
            sm += (evA + evB) + (evC + evD);
            a0 = fmaf(evA, xA.x, fmaf(evB, xB.x, fmaf(evC, xC.x, fmaf(evD, xD.x, a0))));
            a1 = fmaf(evA, xA.y, fmaf(evB, xB.y, fmaf(evC, xC.y, fmaf(evD, xD.y, a1))));

            cA = cE; xA = xE; cB = cF; xB = xF;
            cC = cG; xC = xG; cD = cH; xD = xH;
        }
        // tail (remaining edges already resident in A..D)
        if (k     < e) one(score(xA, __int_as_float(cA.y)), xA);
        if (k + 1 < e) one(score(xB, __int_as_float(cB.y)), xB);
        if (k + 2 < e) one(score(xC, __int_as_float(cC.y)), xC);
        if (k + 3 < e) one(score(xD, __int_as_float(cD.y)), xD);

        float inv = 1.f / (sm + 1e-16f);
        float2 o;
        o.x = a0 * inv;
        o.y = a1 * inv;
        *(float2*)&out_pre[n * HCD + c0] = o;
    }
}

// ---------------------------------------------------------------------------
// K6: BN statistics (per-channel sum & sumsq)
// ---------------------------------------------------------------------------
__global__ __launch_bounds__(128) void bnstat_kernel(const float* __restrict__ out_pre,
                                                     float* __restrict__ stats)
{
    const int t = threadIdx.x;
    float s = 0.f, q = 0.f;
    for (int n = blockIdx.x; n < NN; n += gridDim.x) {
        float v = out_pre[n * HCD + t];
        s += v; q += v * v;
    }
    atomicAdd(&stats[t], s);
    atomicAdd(&stats[HCD + t], q);
}

// ---------------------------------------------------------------------------
// K7: normalize + affine + ELU  (float4)
// ---------------------------------------------------------------------------
__global__ __launch_bounds__(256) void bn_elu_kernel(
    const float* __restrict__ out_pre, const float* __restrict__ stats,
    const float* __restrict__ gamma, const float* __restrict__ beta,
    float* __restrict__ out)
{
    int i4 = blockIdx.x * 256 + threadIdx.x;
    if (i4 >= NN * HCD / 4) return;
    int c4 = (i4 & 31) * 4;
    float4 v = *(const float4*)&out_pre[i4 * 4];
    float o[4] = {v.x, v.y, v.z, v.w};
#pragma unroll
    for (int j = 0; j < 4; ++j) {
        int c = c4 + j;
        float mean = stats[c] * (1.f / NN);
        float var  = stats[HCD + c] * (1.f / NN) - mean * mean;
        float inv  = rsqrtf(var + 1e-5f);
        float t = (o[j] - mean) * inv * gamma[c] + beta[c];
        o[j] = (t > 0.f) ? t : expm1f(t);
    }
    *(float4*)&((float*)out)[i4 * 4] = make_float4(o[0], o[1], o[2], o[3]);
}

// ---------------------------------------------------------------------------
extern "C" void kernel_launch(void* const* d_in, const int* in_sizes, int n_in,
                              void* d_out, int out_size, void* d_ws, size_t ws_size,
                              hipStream_t stream)
{
    (void)in_sizes; (void)n_in; (void)out_size; (void)ws_size;
    const float* x    = (const float*)d_in[0];
    const int*   ei   = (const int*)  d_in[1];
    const float* ea   = (const float*)d_in[2];
    const float* Wl   = (const float*)d_in[3];
    const float* bl   = (const float*)d_in[4];
    const float* Wr   = (const float*)d_in[5];
    const float* br   = (const float*)d_in[6];
    const float* We   = (const float*)d_in[7];
    const float* att  = (const float*)d_in[8];
    const float* gamma= (const float*)d_in[10];
    const float* beta = (const float*)d_in[11];
    float* out = (float*)d_out;

    char* wsb = (char*)d_ws;
    size_t o = 0;
    auto take = [&](size_t bytes) -> char* {
        char* p = wsb + o;
        o += (bytes + 255) & ~size_t(255);
        return p;
    };
    float* xl      = (float*)take(sizeof(float) * NN * HCD);
    float* xr      = (float*)take(sizeof(float) * NN * HCD);
    float* out_pre = (float*)take(sizeof(float) * NN * HCD);
    int2*  csr     = (int2*) take(sizeof(int2)  * NE);
    int*   offs    = (int*)  take(sizeof(int)   * (NN + 1));
    int*   bsum    = (int*)  take(sizeof(int)   * 256);
    int*   boff    = (int*)  take(sizeof(int)   * 256);
    size_t zbytes  = sizeof(int) * NN * 2 + sizeof(float) * 2 * HCD + sizeof(int) * 64;
    char*  zbase   = take(zbytes);
    int*   deg     = (int*)zbase;
    int*   cursor  = deg + NN;
    float* stats   = (float*)(cursor + NN);
    int*   wq      = (int*)(stats + 2 * HCD);

    hipMemsetAsync(zbase, 0, zbytes, stream);

    const int* srcI = ei;
    const int* dstI = ei + NE;

    gemm_mfma<<<dim3((NN + BM - 1) / BM, 2), 256, 65536, stream>>>(
        x, Wl, Wr, bl, br, xl, xr);
    deg_kernel<<<(NE + 255) / 256, 256, 0, stream>>>(dstI, deg);
    scan1<<<SB, 256, 0, stream>>>(deg, bsum);
    scan2<<<1, 256, 0, stream>>>(bsum, boff);
    scan3<<<SB, 256, 0, stream>>>(deg, boff, offs);
    fill_kernel<<<(NE + 255) / 256, 256, 0, stream>>>(srcI, dstI, ea, offs, cursor, csr);
    node_kernel<<<2048, 256, 0, stream>>>(xl, xr, We, att, offs, csr, wq, out_pre);
    bnstat_kernel<<<512, 128, 0, stream>>>(out_pre, stats);
    bn_elu_kernel<<<(NN * HCD / 4 + 255) / 256, 256, 0, stream>>>(out_pre, stats,
                                                                  gamma, beta, out);
}

// Round 5
// 332.573 us; speedup vs baseline: 2.6692x; 2.6692x over previous
//
#include <hip/hip_runtime.h>
#include <math.h>

constexpr int NN  = 50000;   // nodes
constexpr int NE  = 800000;  // edges
constexpr int IND = 128;     // input dim
constexpr int HCD = 128;     // heads*channels
constexpr float NEG_SLOPE = 0.2f;

// persistent node-kernel geometry
constexpr int NBLK   = 2048;            // blocks (all co-resident: 32 waves/CU)
constexpr int NWAVE  = NBLK * 4;        // 8192 waves
constexpr int NQ     = 16;              // work queues
constexpr int WPQ    = NWAVE / NQ;      // 512 waves per queue
constexpr int NPQ    = NN / NQ;         // 3125 nodes per queue
constexpr int CH     = 3;               // nodes per chunk

typedef __attribute__((ext_vector_type(8))) short bf16x8;
typedef __attribute__((ext_vector_type(4))) float f32x4;

// split fp32 -> bf16 hi + bf16 lo (truncation; lo catches the residual).
__device__ __forceinline__ void splitbf(float f, unsigned short &h, unsigned short &lo) {
    unsigned u = __float_as_uint(f);
    h = (unsigned short)(u >> 16);
    float fh = __uint_as_float(u & 0xffff0000u);
    lo = (unsigned short)(__float_as_uint(f - fh) >> 16);
}

// ---------------------------------------------------------------------------
// K1: MFMA split-bf16 GEMM (grid.y: 0 -> xl = x@Wl+bl, 1 -> xr = x@Wr+br)
// ---------------------------------------------------------------------------
constexpr int BM = 128;
constexpr int BK = 64;

__global__ __launch_bounds__(256) void gemm_mfma(
    const float* __restrict__ x, const float* __restrict__ Wl,
    const float* __restrict__ Wr, const float* __restrict__ bl,
    const float* __restrict__ br, float* __restrict__ xl, float* __restrict__ xr)
{
    extern __shared__ char smem[];      // 64 KB
    char* Ah = smem;                    // [128][64] bf16
    char* Al = smem + 16384;
    char* Bh = smem + 32768;            // [c=128][k=64] bf16 (W transposed)
    char* Bl = smem + 49152;

    const int tid = threadIdx.x;
    const float* W  = blockIdx.y ? Wr : Wl;
    const float* bv = blockIdx.y ? br : bl;
    float* outp     = blockIdx.y ? xr : xl;
    const int bn = blockIdx.x * BM;

    const int l   = tid & 63;
    const int wid = tid >> 6;
    const int wr  = (wid >> 1) * 64;
    const int wc  = (wid & 1) * 64;
    const int lr  = l & 15;
    const int kg  = l >> 4;

    f32x4 acc[4][4];
#pragma unroll
    for (int s = 0; s < 4; ++s)
#pragma unroll
        for (int f = 0; f < 4; ++f) acc[s][f] = (f32x4){0.f, 0.f, 0.f, 0.f};

    const int cB  = tid & 127;
    const int khB = tid >> 7;

    for (int ki = 0; ki < 2; ++ki) {
#pragma unroll
        for (int r = 0; r < 8; ++r) {
            int g = tid + r * 256;
            int row = g >> 4, k4 = g & 15;
            int node = bn + row;
            float4 v = make_float4(0.f, 0.f, 0.f, 0.f);
            if (node < NN) v = *(const float4*)&x[node * IND + ki * BK + k4 * 4];
            unsigned short h0, h1, h2, h3, q0, q1, q2, q3;
            splitbf(v.x, h0, q0); splitbf(v.y, h1, q1);
            splitbf(v.z, h2, q2); splitbf(v.w, h3, q3);
            int off = (row * BK + k4 * 4) * 2;
            int swz = off ^ ((row & 7) << 4);
            *(ushort4*)(Ah + swz) = make_ushort4(h0, h1, h2, h3);
            *(ushort4*)(Al + swz) = make_ushort4(q0, q1, q2, q3);
        }
#pragma unroll
        for (int r = 0; r < 8; ++r) {
            int kb = r * 8 + khB * 4;
            float f0 = W[(ki * BK + kb + 0) * HCD + cB];
            float f1 = W[(ki * BK + kb + 1) * HCD + cB];
            float f2 = W[(ki * BK + kb + 2) * HCD + cB];
            float f3 = W[(ki * BK + kb + 3) * HCD + cB];
            unsigned short h0, h1, h2, h3, q0, q1, q2, q3;
            splitbf(f0, h0, q0); splitbf(f1, h1, q1);
            splitbf(f2, h2, q2); splitbf(f3, h3, q3);
            int off = (cB * BK + kb) * 2;
            int swz = off ^ ((cB & 7) << 4);
            *(ushort4*)(Bh + swz) = make_ushort4(h0, h1, h2, h3);
            *(ushort4*)(Bl + swz) = make_ushort4(q0, q1, q2, q3);
        }
        __syncthreads();
#pragma unroll
        for (int kk = 0; kk < 2; ++kk) {
            bf16x8 Bfh[4], Bfl[4];
#pragma unroll
            for (int f = 0; f < 4; ++f) {
                int c = wc + f * 16 + lr;
                int swz = (c * 128 + kk * 64 + kg * 16) ^ ((c & 7) << 4);
                Bfh[f] = *(const bf16x8*)(Bh + swz);
                Bfl[f] = *(const bf16x8*)(Bl + swz);
            }
#pragma unroll
            for (int s = 0; s < 4; ++s) {
                int row = wr + s * 16 + lr;
                int swz = (row * 128 + kk * 64 + kg * 16) ^ ((row & 7) << 4);
                bf16x8 Afh = *(const bf16x8*)(Ah + swz);
                bf16x8 Afl = *(const bf16x8*)(Al + swz);
#pragma unroll
                for (int f = 0; f < 4; ++f) {
                    acc[s][f] = __builtin_amdgcn_mfma_f32_16x16x32_bf16(Afh, Bfh[f], acc[s][f], 0, 0, 0);
                    acc[s][f] = __builtin_amdgcn_mfma_f32_16x16x32_bf16(Afh, Bfl[f], acc[s][f], 0, 0, 0);
                    acc[s][f] = __builtin_amdgcn_mfma_f32_16x16x32_bf16(Afl, Bfh[f], acc[s][f], 0, 0, 0);
                }
            }
        }
        __syncthreads();
    }
#pragma unroll
    for (int s = 0; s < 4; ++s)
#pragma unroll
        for (int f = 0; f < 4; ++f) {
            int c = wc + f * 16 + lr;
            float bb = bv[c];
#pragma unroll
            for (int j = 0; j < 4; ++j) {
                int r = bn + wr + s * 16 + kg * 4 + j;
                if (r < NN) outp[r * HCD + c] = acc[s][f][j] + bb;
            }
        }
}

// ---------------------------------------------------------------------------
// K2: in-degree count
// ---------------------------------------------------------------------------
__global__ __launch_bounds__(256) void deg_kernel(const int* __restrict__ dst,
                                                  int* __restrict__ deg)
{
    int e = blockIdx.x * 256 + threadIdx.x;
    if (e < NE) atomicAdd(&deg[dst[e]], 1);
}

// ---------------------------------------------------------------------------
// K3a/b/c: 3-phase coalesced exclusive scan of deg -> off
// ---------------------------------------------------------------------------
constexpr int SB = (NN + 255) / 256;   // 196 scan blocks

__global__ __launch_bounds__(256) void scan1(const int* __restrict__ deg,
                                             int* __restrict__ bsum)
{
    __shared__ int red[4];
    int idx = blockIdx.x * 256 + threadIdx.x;
    int v = (idx < NN) ? deg[idx] : 0;
    for (int d = 32; d; d >>= 1) v += __shfl_down(v, d);
    if ((threadIdx.x & 63) == 0) red[threadIdx.x >> 6] = v;
    __syncthreads();
    if (threadIdx.x == 0) bsum[blockIdx.x] = red[0] + red[1] + red[2] + red[3];
}

__global__ __launch_bounds__(256) void scan2(const int* __restrict__ bsum,
                                             int* __restrict__ boff)
{
    __shared__ int t[256];
    int tid = threadIdx.x;
    int v = (tid < SB) ? bsum[tid] : 0;
    t[tid] = v;
    __syncthreads();
    for (int d = 1; d < 256; d <<= 1) {
        int u = (tid >= d) ? t[tid - d] : 0;
        __syncthreads();
        t[tid] += u;
        __syncthreads();
    }
    boff[tid] = t[tid] - v;
}

__global__ __launch_bounds__(256) void scan3(const int* __restrict__ deg,
                                             const int* __restrict__ boff,
                                             int* __restrict__ off)
{
    __shared__ int t[256];
    int tid = threadIdx.x;
    int idx = blockIdx.x * 256 + tid;
    int v = (idx < NN) ? deg[idx] : 0;
    t[tid] = v;
    __syncthreads();
    for (int d = 1; d < 256; d <<= 1) {
        int u = (tid >= d) ? t[tid - d] : 0;
        __syncthreads();
        t[tid] += u;
        __syncthreads();
    }
    int excl = t[tid] - v + boff[blockIdx.x];
    if (idx < NN) off[idx] = excl;
    if (idx == NN - 1) off[NN] = excl + v;
}

// ---------------------------------------------------------------------------
// K4: CSR fill — packed (src, ea) int2, single 8B store per edge
// ---------------------------------------------------------------------------
__global__ __launch_bounds__(256) void fill_kernel(
    const int* __restrict__ src, const int* __restrict__ dst,
    const float* __restrict__ ea, const int* __restrict__ off,
    int* __restrict__ cursor, int2* __restrict__ csr)
{
    int e = blockIdx.x * 256 + threadIdx.x;
    if (e >= NE) return;
    int d = dst[e];
    int pos = atomicAdd(&cursor[d], 1);
    csr[off[d] + pos] = make_int2(src[e], __float_as_int(ea[e]));
}

// ---------------------------------------------------------------------------
// K5: persistent node kernel with 16 low-contention chunked work queues.
// Wave gw serves queue q=gw>>9 (nodes [q*NPQ,(q+1)*NPQ)); first chunk is
// static (=rank within queue), further chunks popped 3-nodes-at-a-time from
// qctr[q] (own 256B line, ~1k atomics/queue total). Per node: 4-edge unroll,
// 4-deep prefetch, defer-max online softmax. bias omitted (cancels in BN).
// ---------------------------------------------------------------------------
__global__ __launch_bounds__(256) void node_kernel(
    const float* __restrict__ xl, const float* __restrict__ xr,
    const float* __restrict__ We, const float* __restrict__ att,
    const int* __restrict__ off, const int2* __restrict__ csr,
    int* __restrict__ qctr, float* __restrict__ out_pre)
{
    const int l  = threadIdx.x & 63;
    const int c0 = l * 2;
    const float2 wev = *(const float2*)&We[c0];
    const float2 atv = *(const float2*)&att[c0];

    const int gw    = blockIdx.x * 4 + (threadIdx.x >> 6);
    const int q     = gw >> 9;          // 0..15
    const int rank  = gw & (WPQ - 1);
    const int nbase = q * NPQ;

    int chunk = rank;                    // static first chunk
    for (;;) {
        int n0 = chunk * CH;
        if (n0 >= NPQ) break;
        int n1 = n0 + CH; if (n1 > NPQ) n1 = NPQ;

        for (int n = nbase + n0; n < nbase + n1; ++n) {
            const float2 xrv = *(const float2*)&xr[n * HCD + c0];
            const int s = off[n], e = off[n + 1];

            float mx = -3.402823466e38f, sm = 0.f, a0 = 0.f, a1 = 0.f;

            auto score = [&](float2 xlv, float eav) -> float {
                float m0 = xlv.x + xrv.x + eav * wev.x;
                float m1 = xlv.y + xrv.y + eav * wev.y;
                m0 = (m0 > 0.f) ? m0 : NEG_SLOPE * m0;
                m1 = (m1 > 0.f) ? m1 : NEG_SLOPE * m1;
                float p = m0 * atv.x + m1 * atv.y;
                p += __shfl_xor(p, 8);
                p += __shfl_xor(p, 4);
                p += __shfl_xor(p, 2);
                p += __shfl_xor(p, 1);
                return p;
            };
            auto one = [&](float p, float2 xv) {
                if (p > mx + 8.f) {
                    float sc = __expf(mx - p);
                    sm *= sc; a0 *= sc; a1 *= sc; mx = p;
                }
                float ev = __expf(p - mx);
                sm += ev;
                a0 = fmaf(ev, xv.x, a0);
                a1 = fmaf(ev, xv.y, a1);
            };

            int k = s;
            int2 cA, cB, cC, cD; float2 xA, xB, xC, xD;
            if (k     < e) { cA = csr[k];     xA = *(const float2*)&xl[cA.x * HCD + c0]; }
            if (k + 1 < e) { cB = csr[k + 1]; xB = *(const float2*)&xl[cB.x * HCD + c0]; }
            if (k + 2 < e) { cC = csr[k + 2]; xC = *(const float2*)&xl[cC.x * HCD + c0]; }
            if (k + 3 < e) { cD = csr[k + 3]; xD = *(const float2*)&xl[cD.x * HCD + c0]; }

            for (; k + 4 <= e; k += 4) {
                int2 cE, cF, cG, cH; float2 xE, xF, xG, xH;
                if (k + 4 < e) { cE = csr[k + 4]; xE = *(const float2*)&xl[cE.x * HCD + c0]; }
                if (k + 5 < e) { cF = csr[k + 5]; xF = *(const float2*)&xl[cF.x * HCD + c0]; }
                if (k + 6 < e) { cG = csr[k + 6]; xG = *(const float2*)&xl[cG.x * HCD + c0]; }
                if (k + 7 < e) { cH = csr[k + 7]; xH = *(const float2*)&xl[cH.x * HCD + c0]; }

                float pA = score(xA, __int_as_float(cA.y));
                float pB = score(xB, __int_as_float(cB.y));
                float pC = score(xC, __int_as_float(cC.y));
                float pD = score(xD, __int_as_float(cD.y));
                float pm = fmaxf(fmaxf(pA, pB), fmaxf(pC, pD));
                if (pm > mx + 8.f) {
                    float sc = __expf(mx - pm);
                    sm *= sc; a0 *= sc; a1 *= sc; mx = pm;
                }
                float evA = __expf(pA - mx);
                float evB = __expf(pB - mx);
                float evC = __expf(pC - mx);
                float evD = __expf(pD - mx);
                sm += (evA + evB) + (evC + evD);
                a0 = fmaf(evA, xA.x, fmaf(evB, xB.x, fmaf(evC, xC.x, fmaf(evD, xD.x, a0))));
                a1 = fmaf(evA, xA.y, fmaf(evB, xB.y, fmaf(evC, xC.y, fmaf(evD, xD.y, a1))));

                cA = cE; xA = xE; cB = cF; xB = xF;
                cC = cG; xC = xG; cD = cH; xD = xH;
            }
            if (k     < e) one(score(xA, __int_as_float(cA.y)), xA);
            if (k + 1 < e) one(score(xB, __int_as_float(cB.y)), xB);
            if (k + 2 < e) one(score(xC, __int_as_float(cC.y)), xC);
            if (k + 3 < e) one(score(xD, __int_as_float(cD.y)), xD);

            float inv = 1.f / (sm + 1e-16f);
            float2 o;
            o.x = a0 * inv;
            o.y = a1 * inv;
            *(float2*)&out_pre[n * HCD + c0] = o;
        }

        int t = 0;
        if (l == 0) t = atomicAdd(&qctr[q * 64], 1);
        t = __shfl(t, 0);
        chunk = WPQ + t;                 // counter is biased by the static chunks
    }
}

// ---------------------------------------------------------------------------
// K6: BN statistics (per-channel sum & sumsq)
// ---------------------------------------------------------------------------
__global__ __launch_bounds__(128) void bnstat_kernel(const float* __restrict__ out_pre,
                                                     float* __restrict__ stats)
{
    const int t = threadIdx.x;
    float s = 0.f, q = 0.f;
    for (int n = blockIdx.x; n < NN; n += gridDim.x) {
        float v = out_pre[n * HCD + t];
        s += v; q += v * v;
    }
    atomicAdd(&stats[t], s);
    atomicAdd(&stats[HCD + t], q);
}

// ---------------------------------------------------------------------------
// K7: normalize + affine + ELU  (float4)
// ---------------------------------------------------------------------------
__global__ __launch_bounds__(256) void bn_elu_kernel(
    const float* __restrict__ out_pre, const float* __restrict__ stats,
    const float* __restrict__ gamma, const float* __restrict__ beta,
    float* __restrict__ out)
{
    int i4 = blockIdx.x * 256 + threadIdx.x;
    if (i4 >= NN * HCD / 4) return;
    int c4 = (i4 & 31) * 4;
    float4 v = *(const float4*)&out_pre[i4 * 4];
    float o[4] = {v.x, v.y, v.z, v.w};
#pragma unroll
    for (int j = 0; j < 4; ++j) {
        int c = c4 + j;
        float mean = stats[c] * (1.f / NN);
        float var  = stats[HCD + c] * (1.f / NN) - mean * mean;
        float inv  = rsqrtf(var + 1e-5f);
        float t = (o[j] - mean) * inv * gamma[c] + beta[c];
        o[j] = (t > 0.f) ? t : expm1f(t);
    }
    *(float4*)&((float*)out)[i4 * 4] = make_float4(o[0], o[1], o[2], o[3]);
}

// ---------------------------------------------------------------------------
extern "C" void kernel_launch(void* const* d_in, const int* in_sizes, int n_in,
                              void* d_out, int out_size, void* d_ws, size_t ws_size,
                              hipStream_t stream)
{
    (void)in_sizes; (void)n_in; (void)out_size; (void)ws_size;
    const float* x    = (const float*)d_in[0];
    const int*   ei   = (const int*)  d_in[1];
    const float* ea   = (const float*)d_in[2];
    const float* Wl   = (const float*)d_in[3];
    const float* bl   = (const float*)d_in[4];
    const float* Wr   = (const float*)d_in[5];
    const float* br   = (const float*)d_in[6];
    const float* We   = (const float*)d_in[7];
    const float* att  = (const float*)d_in[8];
    const float* gamma= (const float*)d_in[10];
    const float* beta = (const float*)d_in[11];
    float* out = (float*)d_out;

    char* wsb = (char*)d_ws;
    size_t o = 0;
    auto take = [&](size_t bytes) -> char* {
        char* p = wsb + o;
        o += (bytes + 255) & ~size_t(255);
        return p;
    };
    float* xl      = (float*)take(sizeof(float) * NN * HCD);
    float* xr      = (float*)take(sizeof(float) * NN * HCD);
    float* out_pre = (float*)take(sizeof(float) * NN * HCD);
    int2*  csr     = (int2*) take(sizeof(int2)  * NE);
    int*   offs    = (int*)  take(sizeof(int)   * (NN + 1));
    int*   bsum    = (int*)  take(sizeof(int)   * 256);
    int*   boff    = (int*)  take(sizeof(int)   * 256);
    size_t zbytes  = sizeof(int) * NN * 2 + sizeof(float) * 2 * HCD
                   + sizeof(int) * NQ * 64;
    char*  zbase   = take(zbytes);
    int*   deg     = (int*)zbase;
    int*   cursor  = deg + NN;
    float* stats   = (float*)(cursor + NN);
    int*   qctr    = (int*)(stats + 2 * HCD);

    hipMemsetAsync(zbase, 0, zbytes, stream);

    const int* srcI = ei;
    const int* dstI = ei + NE;

    gemm_mfma<<<dim3((NN + BM - 1) / BM, 2), 256, 65536, stream>>>(
        x, Wl, Wr, bl, br, xl, xr);
    deg_kernel<<<(NE + 255) / 256, 256, 0, stream>>>(dstI, deg);
    scan1<<<SB, 256, 0, stream>>>(deg, bsum);
    scan2<<<1, 256, 0, stream>>>(bsum, boff);
    scan3<<<SB, 256, 0, stream>>>(deg, boff, offs);
    fill_kernel<<<(NE + 255) / 256, 256, 0, stream>>>(srcI, dstI, ea, offs, cursor, csr);
    node_kernel<<<NBLK, 256, 0, stream>>>(xl, xr, We, att, offs, csr, qctr, out_pre);
    bnstat_kernel<<<512, 128, 0, stream>>>(out_pre, stats);
    bn_elu_kernel<<<(NN * HCD / 4 + 255) / 256, 256, 0, stream>>>(out_pre, stats,
                                                                  gamma, beta, out);
}

// Round 6
// 239.819 us; speedup vs baseline: 3.7016x; 1.3868x over previous
//
#include <hip/hip_runtime.h>
#include <math.h>

constexpr int NN  = 50000;   // nodes
constexpr int NE  = 800000;  // edges
constexpr int IND = 128;     // input dim
constexpr int HCD = 128;     // heads*channels

typedef __attribute__((ext_vector_type(8))) short bf16x8;
typedef __attribute__((ext_vector_type(4))) float f32x4;

// split fp32 -> bf16 hi + bf16 lo (truncation; lo catches the residual).
__device__ __forceinline__ void splitbf(float f, unsigned short &h, unsigned short &lo) {
    unsigned u = __float_as_uint(f);
    h = (unsigned short)(u >> 16);
    float fh = __uint_as_float(u & 0xffff0000u);
    lo = (unsigned short)(__float_as_uint(f - fh) >> 16);
}
// fp32 -> bf16 RNE
__device__ __forceinline__ unsigned short bf16rne(float f) {
    unsigned u = __float_as_uint(f);
    u += 0x7fffu + ((u >> 16) & 1u);
    return (unsigned short)(u >> 16);
}

// ---------------------------------------------------------------------------
// K1: MFMA split-bf16 GEMM.  grid.y==0: xl_bf16 = bf16(x@Wl + bl)
//                            grid.y==1: xr      = x@Wr + br  (fp32)
// 2-term accumulation (hiA+loA)*hiB  => W is bf16-rounded, x near-exact.
// Block 256 thr, tile 128x128, BK=64, LDS 48KB (3 blocks/CU).
// ---------------------------------------------------------------------------
constexpr int BM = 128;
constexpr int BK = 64;

__global__ __launch_bounds__(256) void gemm_mfma(
    const float* __restrict__ x, const float* __restrict__ Wl,
    const float* __restrict__ Wr, const float* __restrict__ bl,
    const float* __restrict__ br, unsigned short* __restrict__ xlbf,
    float* __restrict__ xr)
{
    extern __shared__ char smem[];      // 48 KB
    char* Ah = smem;                    // [128][64] bf16
    char* Al = smem + 16384;
    char* Bh = smem + 32768;            // [c=128][k=64] bf16 (W transposed)

    const int tid = threadIdx.x;
    const float* W  = blockIdx.y ? Wr : Wl;
    const float* bv = blockIdx.y ? br : bl;
    const int bn = blockIdx.x * BM;

    const int l   = tid & 63;
    const int wid = tid >> 6;
    const int wr  = (wid >> 1) * 64;
    const int wc  = (wid & 1) * 64;
    const int lr  = l & 15;
    const int kg  = l >> 4;

    f32x4 acc[4][4];
#pragma unroll
    for (int s = 0; s < 4; ++s)
#pragma unroll
        for (int f = 0; f < 4; ++f) acc[s][f] = (f32x4){0.f, 0.f, 0.f, 0.f};

    const int cB  = tid & 127;
    const int khB = tid >> 7;

    for (int ki = 0; ki < 2; ++ki) {
#pragma unroll
        for (int r = 0; r < 8; ++r) {
            int g = tid + r * 256;
            int row = g >> 4, k4 = g & 15;
            int node = bn + row;
            float4 v = make_float4(0.f, 0.f, 0.f, 0.f);
            if (node < NN) v = *(const float4*)&x[node * IND + ki * BK + k4 * 4];
            unsigned short h0, h1, h2, h3, q0, q1, q2, q3;
            splitbf(v.x, h0, q0); splitbf(v.y, h1, q1);
            splitbf(v.z, h2, q2); splitbf(v.w, h3, q3);
            int off = (row * BK + k4 * 4) * 2;
            int swz = off ^ ((row & 7) << 4);
            *(ushort4*)(Ah + swz) = make_ushort4(h0, h1, h2, h3);
            *(ushort4*)(Al + swz) = make_ushort4(q0, q1, q2, q3);
        }
#pragma unroll
        for (int r = 0; r < 8; ++r) {
            int kb = r * 8 + khB * 4;
            float f0 = W[(ki * BK + kb + 0) * HCD + cB];
            float f1 = W[(ki * BK + kb + 1) * HCD + cB];
            float f2 = W[(ki * BK + kb + 2) * HCD + cB];
            float f3 = W[(ki * BK + kb + 3) * HCD + cB];
            int off = (cB * BK + kb) * 2;
            int swz = off ^ ((cB & 7) << 4);
            *(ushort4*)(Bh + swz) = make_ushort4(bf16rne(f0), bf16rne(f1),
                                                 bf16rne(f2), bf16rne(f3));
        }
        __syncthreads();
#pragma unroll
        for (int kk = 0; kk < 2; ++kk) {
            bf16x8 Bfh[4];
#pragma unroll
            for (int f = 0; f < 4; ++f) {
                int c = wc + f * 16 + lr;
                int swz = (c * 128 + kk * 64 + kg * 16) ^ ((c & 7) << 4);
                Bfh[f] = *(const bf16x8*)(Bh + swz);
            }
#pragma unroll
            for (int s = 0; s < 4; ++s) {
                int row = wr + s * 16 + lr;
                int swz = (row * 128 + kk * 64 + kg * 16) ^ ((row & 7) << 4);
                bf16x8 Afh = *(const bf16x8*)(Ah + swz);
                bf16x8 Afl = *(const bf16x8*)(Al + swz);
#pragma unroll
                for (int f = 0; f < 4; ++f) {
                    acc[s][f] = __builtin_amdgcn_mfma_f32_16x16x32_bf16(Afh, Bfh[f], acc[s][f], 0, 0, 0);
                    acc[s][f] = __builtin_amdgcn_mfma_f32_16x16x32_bf16(Afl, Bfh[f], acc[s][f], 0, 0, 0);
                }
            }
        }
        __syncthreads();
    }
#pragma unroll
    for (int s = 0; s < 4; ++s)
#pragma unroll
        for (int f = 0; f < 4; ++f) {
            int c = wc + f * 16 + lr;
            float bb = bv[c];
#pragma unroll
            for (int j = 0; j < 4; ++j) {
                int r = bn + wr + s * 16 + kg * 4 + j;
                if (r >= NN) continue;
                float v = acc[s][f][j] + bb;
                if (blockIdx.y) xr[r * HCD + c] = v;
                else            xlbf[r * HCD + c] = bf16rne(v);
            }
        }
}

// ---------------------------------------------------------------------------
// K2: in-degree count
// ---------------------------------------------------------------------------
__global__ __launch_bounds__(256) void deg_kernel(const int* __restrict__ dst,
                                                  int* __restrict__ deg)
{
    int e = blockIdx.x * 256 + threadIdx.x;
    if (e < NE) atomicAdd(&deg[dst[e]], 1);
}

// ---------------------------------------------------------------------------
// K3a/b/c: 3-phase coalesced exclusive scan of deg -> off
// ---------------------------------------------------------------------------
constexpr int SB = (NN + 255) / 256;   // 196 scan blocks

__global__ __launch_bounds__(256) void scan1(const int* __restrict__ deg,
                                             int* __restrict__ bsum)
{
    __shared__ int red[4];
    int idx = blockIdx.x * 256 + threadIdx.x;
    int v = (idx < NN) ? deg[idx] : 0;
    for (int d = 32; d; d >>= 1) v += __shfl_down(v, d);
    if ((threadIdx.x & 63) == 0) red[threadIdx.x >> 6] = v;
    __syncthreads();
    if (threadIdx.x == 0) bsum[blockIdx.x] = red[0] + red[1] + red[2] + red[3];
}

__global__ __launch_bounds__(256) void scan2(const int* __restrict__ bsum,
                                             int* __restrict__ boff)
{
    __shared__ int t[256];
    int tid = threadIdx.x;
    int v = (tid < SB) ? bsum[tid] : 0;
    t[tid] = v;
    __syncthreads();
    for (int d = 1; d < 256; d <<= 1) {
        int u = (tid >= d) ? t[tid - d] : 0;
        __syncthreads();
        t[tid] += u;
        __syncthreads();
    }
    boff[tid] = t[tid] - v;
}

__global__ __launch_bounds__(256) void scan3(const int* __restrict__ deg,
                                             const int* __restrict__ boff,
                                             int* __restrict__ off)
{
    __shared__ int t[256];
    int tid = threadIdx.x;
    int idx = blockIdx.x * 256 + tid;
    int v = (idx < NN) ? deg[idx] : 0;
    t[tid] = v;
    __syncthreads();
    for (int d = 1; d < 256; d <<= 1) {
        int u = (tid >= d) ? t[tid - d] : 0;
        __syncthreads();
        t[tid] += u;
        __syncthreads();
    }
    int excl = t[tid] - v + boff[blockIdx.x];
    if (idx < NN) off[idx] = excl;
    if (idx == NN - 1) off[NN] = excl + v;
}

// ---------------------------------------------------------------------------
// K4: CSR fill — packed (src, ea) int2, single 8B store per edge
// ---------------------------------------------------------------------------
__global__ __launch_bounds__(256) void fill_kernel(
    const int* __restrict__ src, const int* __restrict__ dst,
    const float* __restrict__ ea, const int* __restrict__ off,
    int* __restrict__ cursor, int2* __restrict__ csr)
{
    int e = blockIdx.x * 256 + threadIdx.x;
    if (e >= NE) return;
    int d = dst[e];
    int pos = atomicAdd(&cursor[d], 1);
    csr[off[d] + pos] = make_int2(src[e], __float_as_int(ea[e]));
}

// ---------------------------------------------------------------------------
// K5: node kernel, 1 wave = 1 node. Lane l = 16*g + i: group g (0..3)
// processes edge quad-slot g, lane i owns channels [8i, 8i+8).
// Per edge: one dwordx4 bf16 gather per lane-group, head-reduce = 2 shfls
// (4-lane groups). Per-group online-softmax states merged once at node end.
// bias omitted (cancels in BN).
// ---------------------------------------------------------------------------
__global__ __launch_bounds__(256) void node_kernel(
    const unsigned short* __restrict__ xlbf, const float* __restrict__ xr,
    const float* __restrict__ We, const float* __restrict__ att,
    const int* __restrict__ off, const int2* __restrict__ csr,
    float* __restrict__ out_pre)
{
    const int n = blockIdx.x * 4 + (threadIdx.x >> 6);
    if (n >= NN) return;
    const int l  = threadIdx.x & 63;
    const int g  = l >> 4;
    const int i  = l & 15;
    const int c0 = i * 8;

    float wev[8], atv[8], xrv[8];
    {
        float4 a = *(const float4*)&We[c0],  b = *(const float4*)&We[c0 + 4];
        wev[0]=a.x; wev[1]=a.y; wev[2]=a.z; wev[3]=a.w;
        wev[4]=b.x; wev[5]=b.y; wev[6]=b.z; wev[7]=b.w;
        float4 c = *(const float4*)&att[c0], d = *(const float4*)&att[c0 + 4];
        atv[0]=c.x; atv[1]=c.y; atv[2]=c.z; atv[3]=c.w;
        atv[4]=d.x; atv[5]=d.y; atv[6]=d.z; atv[7]=d.w;
        float4 p = *(const float4*)&xr[(size_t)n * HCD + c0];
        float4 q = *(const float4*)&xr[(size_t)n * HCD + c0 + 4];
        xrv[0]=p.x; xrv[1]=p.y; xrv[2]=p.z; xrv[3]=p.w;
        xrv[4]=q.x; xrv[5]=q.y; xrv[6]=q.z; xrv[7]=q.w;
    }

    const int s = off[n], e = off[n + 1];
    if (s == e) {                       // empty segment: out = 0
        if (g == 0) {
            float4 z = make_float4(0.f, 0.f, 0.f, 0.f);
            *(float4*)&out_pre[(size_t)n * HCD + c0] = z;
            *(float4*)&out_pre[(size_t)n * HCD + c0 + 4] = z;
        }
        return;
    }

    float mx = -3.0e38f, sm = 0.f;
    float acc[8];
#pragma unroll
    for (int c = 0; c < 8; ++c) acc[c] = 0.f;

    // prefetch first quad-slot
    int k = s;
    int2 c2; uint4 xb; bool v;
    {
        int idx = k + g; if (idx > e - 1) idx = e - 1;
        c2 = csr[idx];
        xb = *(const uint4*)&xlbf[(size_t)c2.x * HCD + c0];
        v  = (k + g) < e;
    }

    for (; k < e; k += 4) {
        // prefetch next quad
        int2 c2n; uint4 xbn; bool vn;
        {
            int kn = k + 4 + g; int idx = kn; if (idx > e - 1) idx = e - 1;
            c2n = csr[idx];
            xbn = *(const uint4*)&xlbf[(size_t)c2n.x * HCD + c0];
            vn  = kn < e;
        }
        // unpack bf16 gather
        float xv[8];
        xv[0] = __uint_as_float((c2.y, xb.x << 16));   // placeholder replaced below
        xv[0] = __uint_as_float(xb.x << 16);
        xv[1] = __uint_as_float(xb.x & 0xffff0000u);
        xv[2] = __uint_as_float(xb.y << 16);
        xv[3] = __uint_as_float(xb.y & 0xffff0000u);
        xv[4] = __uint_as_float(xb.z << 16);
        xv[5] = __uint_as_float(xb.z & 0xffff0000u);
        xv[6] = __uint_as_float(xb.w << 16);
        xv[7] = __uint_as_float(xb.w & 0xffff0000u);

        float ea = __int_as_float(c2.y);
        float p = 0.f;
#pragma unroll
        for (int c = 0; c < 8; ++c) {
            float m = fmaf(ea, wev[c], xv[c] + xrv[c]);
            m = fmaxf(m, 0.2f * m);                    // leaky_relu, slope 0.2
            p = fmaf(m, atv[c], p);
        }
        p += __shfl_xor(p, 1);                          // head reduce (4 lanes)
        p += __shfl_xor(p, 2);
        if (!v) p = -1.0e30f;

        if (__any(p > mx + 8.f)) {                      // rare rescale
            float nm = fmaxf(mx, p);
            float sc = __expf(mx - nm);
            sm *= sc;
#pragma unroll
            for (int c = 0; c < 8; ++c) acc[c] *= sc;
            mx = nm;
        }
        float ev = v ? __expf(p - mx) : 0.f;
        sm += ev;
#pragma unroll
        for (int c = 0; c < 8; ++c) acc[c] = fmaf(ev, xv[c], acc[c]);

        c2 = c2n; xb = xbn; v = vn;
    }

    // merge the 4 group states (lanes l, l^16, l^32 hold same channels)
    float M = fmaxf(mx, __shfl_xor(mx, 16));
    M = fmaxf(M, __shfl_xor(M, 32));
    float sc = __expf(mx - M);                          // 0 for empty groups
    float smT = sm * sc;
    smT += __shfl_xor(smT, 16);
    smT += __shfl_xor(smT, 32);
    float inv = 1.f / (smT + 1e-16f);
    float o[8];
#pragma unroll
    for (int c = 0; c < 8; ++c) {
        float a = acc[c] * sc;
        a += __shfl_xor(a, 16);
        a += __shfl_xor(a, 32);
        o[c] = a * inv;
    }
    if (g == 0) {
        *(float4*)&out_pre[(size_t)n * HCD + c0]     = make_float4(o[0], o[1], o[2], o[3]);
        *(float4*)&out_pre[(size_t)n * HCD + c0 + 4] = make_float4(o[4], o[5], o[6], o[7]);
    }
}

// ---------------------------------------------------------------------------
// K6: BN statistics (per-channel sum & sumsq)
// ---------------------------------------------------------------------------
__global__ __launch_bounds__(128) void bnstat_kernel(const float* __restrict__ out_pre,
                                                     float* __restrict__ stats)
{
    const int t = threadIdx.x;
    float s = 0.f, q = 0.f;
    for (int n = blockIdx.x; n < NN; n += gridDim.x) {
        float v = out_pre[n * HCD + t];
        s += v; q += v * v;
    }
    atomicAdd(&stats[t], s);
    atomicAdd(&stats[HCD + t], q);
}

// ---------------------------------------------------------------------------
// K7: normalize + affine + ELU  (float4)
// ---------------------------------------------------------------------------
__global__ __launch_bounds__(256) void bn_elu_kernel(
    const float* __restrict__ out_pre, const float* __restrict__ stats,
    const float* __restrict__ gamma, const float* __restrict__ beta,
    float* __restrict__ out)
{
    int i4 = blockIdx.x * 256 + threadIdx.x;
    if (i4 >= NN * HCD / 4) return;
    int c4 = (i4 & 31) * 4;
    float4 v = *(const float4*)&out_pre[i4 * 4];
    float o[4] = {v.x, v.y, v.z, v.w};
#pragma unroll
    for (int j = 0; j < 4; ++j) {
        int c = c4 + j;
        float mean = stats[c] * (1.f / NN);
        float var  = stats[HCD + c] * (1.f / NN) - mean * mean;
        float inv  = rsqrtf(var + 1e-5f);
        float t = (o[j] - mean) * inv * gamma[c] + beta[c];
        o[j] = (t > 0.f) ? t : expm1f(t);
    }
    *(float4*)&((float*)out)[i4 * 4] = make_float4(o[0], o[1], o[2], o[3]);
}

// ---------------------------------------------------------------------------
extern "C" void kernel_launch(void* const* d_in, const int* in_sizes, int n_in,
                              void* d_out, int out_size, void* d_ws, size_t ws_size,
                              hipStream_t stream)
{
    (void)in_sizes; (void)n_in; (void)out_size; (void)ws_size;
    const float* x    = (const float*)d_in[0];
    const int*   ei   = (const int*)  d_in[1];
    const float* ea   = (const float*)d_in[2];
    const float* Wl   = (const float*)d_in[3];
    const float* bl   = (const float*)d_in[4];
    const float* Wr   = (const float*)d_in[5];
    const float* br   = (const float*)d_in[6];
    const float* We   = (const float*)d_in[7];
    const float* att  = (const float*)d_in[8];
    const float* gamma= (const float*)d_in[10];
    const float* beta = (const float*)d_in[11];
    float* out = (float*)d_out;

    char* wsb = (char*)d_ws;
    size_t o = 0;
    auto take = [&](size_t bytes) -> char* {
        char* p = wsb + o;
        o += (bytes + 255) & ~size_t(255);
        return p;
    };
    unsigned short* xlbf = (unsigned short*)take(sizeof(unsigned short) * NN * HCD);
    float* xr      = (float*)take(sizeof(float) * NN * HCD);
    float* out_pre = (float*)take(sizeof(float) * NN * HCD);
    int2*  csr     = (int2*) take(sizeof(int2)  * NE);
    int*   offs    = (int*)  take(sizeof(int)   * (NN + 1));
    int*   bsum    = (int*)  take(sizeof(int)   * 256);
    int*   boff    = (int*)  take(sizeof(int)   * 256);
    size_t zbytes  = sizeof(int) * NN * 2 + sizeof(float) * 2 * HCD;
    char*  zbase   = take(zbytes);
    int*   deg     = (int*)zbase;
    int*   cursor  = deg + NN;
    float* stats   = (float*)(cursor + NN);

    hipMemsetAsync(zbase, 0, zbytes, stream);

    const int* srcI = ei;
    const int* dstI = ei + NE;

    gemm_mfma<<<dim3((NN + BM - 1) / BM, 2), 256, 49152, stream>>>(
        x, Wl, Wr, bl, br, xlbf, xr);
    deg_kernel<<<(NE + 255) / 256, 256, 0, stream>>>(dstI, deg);
    scan1<<<SB, 256, 0, stream>>>(deg, bsum);
    scan2<<<1, 256, 0, stream>>>(bsum, boff);
    scan3<<<SB, 256, 0, stream>>>(deg, boff, offs);
    fill_kernel<<<(NE + 255) / 256, 256, 0, stream>>>(srcI, dstI, ea, offs, cursor, csr);
    node_kernel<<<(NN + 3) / 4, 256, 0, stream>>>(xlbf, xr, We, att, offs, csr, out_pre);
    bnstat_kernel<<<512, 128, 0, stream>>>(out_pre, stats);
    bn_elu_kernel<<<(NN * HCD / 4 + 255) / 256, 256, 0, stream>>>(out_pre, stats,
                                                                  gamma, beta, out);
}

// Round 7
// 232.182 us; speedup vs baseline: 3.8233x; 1.0329x over previous
//
#include <hip/hip_runtime.h>
#include <math.h>

constexpr int NN  = 50000;   // nodes
constexpr int NE  = 800000;  // edges
constexpr int IND = 128;     // input dim
constexpr int HCD = 128;     // heads*channels

// bucketed CSR-fill geometry
constexpr int NBKT = 16;               // dst-range buckets
constexpr int NPB  = NN / NBKT;        // 3125 nodes per bucket
constexpr int BCAP = 65536;            // staging capacity per bucket (mean 50k)
constexpr int BE   = 4096;             // edges per bucket_kernel block
constexpr int B1B  = (NE + BE - 1) / BE;

typedef __attribute__((ext_vector_type(8))) short bf16x8;
typedef __attribute__((ext_vector_type(4))) float f32x4;

__device__ __forceinline__ void splitbf(float f, unsigned short &h, unsigned short &lo) {
    unsigned u = __float_as_uint(f);
    h = (unsigned short)(u >> 16);
    float fh = __uint_as_float(u & 0xffff0000u);
    lo = (unsigned short)(__float_as_uint(f - fh) >> 16);
}
__device__ __forceinline__ unsigned short bf16rne(float f) {
    unsigned u = __float_as_uint(f);
    u += 0x7fffu + ((u >> 16) & 1u);
    return (unsigned short)(u >> 16);
}

// ---------------------------------------------------------------------------
// K1: MFMA split-bf16 GEMM.  grid.y==0: xl_bf16 = bf16(x@Wl + bl)
//                            grid.y==1: xr      = x@Wr + br  (fp32)
// ---------------------------------------------------------------------------
constexpr int BM = 128;
constexpr int BK = 64;

__global__ __launch_bounds__(256) void gemm_mfma(
    const float* __restrict__ x, const float* __restrict__ Wl,
    const float* __restrict__ Wr, const float* __restrict__ bl,
    const float* __restrict__ br, unsigned short* __restrict__ xlbf,
    float* __restrict__ xr)
{
    extern __shared__ char smem[];      // 48 KB
    char* Ah = smem;                    // [128][64] bf16
    char* Al = smem + 16384;
    char* Bh = smem + 32768;            // [c=128][k=64] bf16 (W transposed)

    const int tid = threadIdx.x;
    const float* W  = blockIdx.y ? Wr : Wl;
    const float* bv = blockIdx.y ? br : bl;
    const int bn = blockIdx.x * BM;

    const int l   = tid & 63;
    const int wid = tid >> 6;
    const int wr  = (wid >> 1) * 64;
    const int wc  = (wid & 1) * 64;
    const int lr  = l & 15;
    const int kg  = l >> 4;

    f32x4 acc[4][4];
#pragma unroll
    for (int s = 0; s < 4; ++s)
#pragma unroll
        for (int f = 0; f < 4; ++f) acc[s][f] = (f32x4){0.f, 0.f, 0.f, 0.f};

    const int cB  = tid & 127;
    const int khB = tid >> 7;

    for (int ki = 0; ki < 2; ++ki) {
#pragma unroll
        for (int r = 0; r < 8; ++r) {
            int g = tid + r * 256;
            int row = g >> 4, k4 = g & 15;
            int node = bn + row;
            float4 v = make_float4(0.f, 0.f, 0.f, 0.f);
            if (node < NN) v = *(const float4*)&x[node * IND + ki * BK + k4 * 4];
            unsigned short h0, h1, h2, h3, q0, q1, q2, q3;
            splitbf(v.x, h0, q0); splitbf(v.y, h1, q1);
            splitbf(v.z, h2, q2); splitbf(v.w, h3, q3);
            int off = (row * BK + k4 * 4) * 2;
            int swz = off ^ ((row & 7) << 4);
            *(ushort4*)(Ah + swz) = make_ushort4(h0, h1, h2, h3);
            *(ushort4*)(Al + swz) = make_ushort4(q0, q1, q2, q3);
        }
#pragma unroll
        for (int r = 0; r < 8; ++r) {
            int kb = r * 8 + khB * 4;
            float f0 = W[(ki * BK + kb + 0) * HCD + cB];
            float f1 = W[(ki * BK + kb + 1) * HCD + cB];
            float f2 = W[(ki * BK + kb + 2) * HCD + cB];
            float f3 = W[(ki * BK + kb + 3) * HCD + cB];
            int off = (cB * BK + kb) * 2;
            int swz = off ^ ((cB & 7) << 4);
            *(ushort4*)(Bh + swz) = make_ushort4(bf16rne(f0), bf16rne(f1),
                                                 bf16rne(f2), bf16rne(f3));
        }
        __syncthreads();
#pragma unroll
        for (int kk = 0; kk < 2; ++kk) {
            bf16x8 Bfh[4];
#pragma unroll
            for (int f = 0; f < 4; ++f) {
                int c = wc + f * 16 + lr;
                int swz = (c * 128 + kk * 64 + kg * 16) ^ ((c & 7) << 4);
                Bfh[f] = *(const bf16x8*)(Bh + swz);
            }
#pragma unroll
            for (int s = 0; s < 4; ++s) {
                int row = wr + s * 16 + lr;
                int swz = (row * 128 + kk * 64 + kg * 16) ^ ((row & 7) << 4);
                bf16x8 Afh = *(const bf16x8*)(Ah + swz);
                bf16x8 Afl = *(const bf16x8*)(Al + swz);
#pragma unroll
                for (int f = 0; f < 4; ++f) {
                    acc[s][f] = __builtin_amdgcn_mfma_f32_16x16x32_bf16(Afh, Bfh[f], acc[s][f], 0, 0, 0);
                    acc[s][f] = __builtin_amdgcn_mfma_f32_16x16x32_bf16(Afl, Bfh[f], acc[s][f], 0, 0, 0);
                }
            }
        }
        __syncthreads();
    }
#pragma unroll
    for (int s = 0; s < 4; ++s)
#pragma unroll
        for (int f = 0; f < 4; ++f) {
            int c = wc + f * 16 + lr;
            float bb = bv[c];
#pragma unroll
            for (int j = 0; j < 4; ++j) {
                int r = bn + wr + s * 16 + kg * 4 + j;
                if (r >= NN) continue;
                float v = acc[s][f][j] + bb;
                if (blockIdx.y) xr[r * HCD + c] = v;
                else            xlbf[r * HCD + c] = bf16rne(v);
            }
        }
}

// ---------------------------------------------------------------------------
// K2: bucket scatter + degree count. Each block: 4096 edges -> LDS-counted
// per-bucket grant (1 global atomic/bucket/block) -> compacted int4
// (src,dst,ea) into per-bucket staging region. deg counting folded in.
// ---------------------------------------------------------------------------
__global__ __launch_bounds__(256) void bucket_kernel(
    const int* __restrict__ src, const int* __restrict__ dst,
    const float* __restrict__ ea, int* __restrict__ gcur,
    int* __restrict__ deg, int4* __restrict__ stg)
{
    __shared__ int cnt[NBKT], base[NBKT];
    const int tid = threadIdx.x;
    if (tid < NBKT) cnt[tid] = 0;
    __syncthreads();

    const int e0 = blockIdx.x * BE;
    int4 v[16]; int nb[16];
#pragma unroll
    for (int j = 0; j < 16; ++j) {
        int e = e0 + j * 256 + tid;
        bool ok = e < NE;
        int s_ = ok ? src[e] : 0;
        int d_ = ok ? dst[e] : 0;
        float a_ = ok ? ea[e] : 0.f;
        v[j]  = make_int4(s_, d_, __float_as_int(a_), 0);
        nb[j] = ok ? (d_ / NPB) : -1;
        if (ok) atomicAdd(&cnt[nb[j]], 1);
    }
    __syncthreads();
    if (tid < NBKT) {
        base[tid] = atomicAdd(&gcur[tid * 16], cnt[tid]);
        cnt[tid] = 0;                    // reuse as local cursor
    }
    __syncthreads();
#pragma unroll
    for (int j = 0; j < 16; ++j) {
        if (nb[j] >= 0) {
            int slot = base[nb[j]] + atomicAdd(&cnt[nb[j]], 1);
            stg[nb[j] * BCAP + slot] = v[j];
            atomicAdd(&deg[v[j].y], 1);
        }
    }
}

// ---------------------------------------------------------------------------
// K3a/b/c: 3-phase coalesced exclusive scan of deg -> off
// ---------------------------------------------------------------------------
constexpr int SB = (NN + 255) / 256;   // 196 scan blocks

__global__ __launch_bounds__(256) void scan1(const int* __restrict__ deg,
                                             int* __restrict__ bsum)
{
    __shared__ int red[4];
    int idx = blockIdx.x * 256 + threadIdx.x;
    int v = (idx < NN) ? deg[idx] : 0;
    for (int d = 32; d; d >>= 1) v += __shfl_down(v, d);
    if ((threadIdx.x & 63) == 0) red[threadIdx.x >> 6] = v;
    __syncthreads();
    if (threadIdx.x == 0) bsum[blockIdx.x] = red[0] + red[1] + red[2] + red[3];
}

__global__ __launch_bounds__(256) void scan2(const int* __restrict__ bsum,
                                             int* __restrict__ boff)
{
    __shared__ int t[256];
    int tid = threadIdx.x;
    int v = (tid < SB) ? bsum[tid] : 0;
    t[tid] = v;
    __syncthreads();
    for (int d = 1; d < 256; d <<= 1) {
        int u = (tid >= d) ? t[tid - d] : 0;
        __syncthreads();
        t[tid] += u;
        __syncthreads();
    }
    boff[tid] = t[tid] - v;
}

__global__ __launch_bounds__(256) void scan3(const int* __restrict__ deg,
                                             const int* __restrict__ boff,
                                             int* __restrict__ off)
{
    __shared__ int t[256];
    int tid = threadIdx.x;
    int idx = blockIdx.x * 256 + tid;
    int v = (idx < NN) ? deg[idx] : 0;
    t[tid] = v;
    __syncthreads();
    for (int d = 1; d < 256; d <<= 1) {
        int u = (tid >= d) ? t[tid - d] : 0;
        __syncthreads();
        t[tid] += u;
        __syncthreads();
    }
    int excl = t[tid] - v + boff[blockIdx.x];
    if (idx < NN) off[idx] = excl;
    if (idx == NN - 1) off[NN] = excl + v;
}

// ---------------------------------------------------------------------------
// K4: CSR fill from staging. Block i -> bucket (i&7)*2 + ((i>>3)&1), so all
// blocks on one XCD (round-robin dispatch) scatter into the same ~400KB csr
// window -> stores merge in that XCD's L2.
// ---------------------------------------------------------------------------
__global__ __launch_bounds__(256) void csrfill_kernel(
    const int4* __restrict__ stg, const int* __restrict__ gcur,
    const int* __restrict__ off, int* __restrict__ cursor,
    int2* __restrict__ csr)
{
    const int i = blockIdx.x;                 // 0..255
    const int b = (i & 7) * 2 + ((i >> 3) & 1);
    const int chunk = i >> 4;                 // 0..15
    const int count = gcur[b * 16];
#pragma unroll
    for (int j = 0; j < 16; ++j) {
        int sl = chunk * (BCAP / 16) + j * 256 + threadIdx.x;
        if (sl < count) {
            int4 v = stg[b * BCAP + sl];
            int pos = off[v.y] + atomicAdd(&cursor[v.y], 1);
            csr[pos] = make_int2(v.x, v.z);
        }
    }
}

// ---------------------------------------------------------------------------
// K5: node kernel, 1 wave = 1 node. Lane l = 16*g + i: group g (0..3)
// processes edge quad-slot g, lane i owns channels [8i, 8i+8).
// ---------------------------------------------------------------------------
__global__ __launch_bounds__(256) void node_kernel(
    const unsigned short* __restrict__ xlbf, const float* __restrict__ xr,
    const float* __restrict__ We, const float* __restrict__ att,
    const int* __restrict__ off, const int2* __restrict__ csr,
    float* __restrict__ out_pre)
{
    const int n = blockIdx.x * 4 + (threadIdx.x >> 6);
    if (n >= NN) return;
    const int l  = threadIdx.x & 63;
    const int g  = l >> 4;
    const int i  = l & 15;
    const int c0 = i * 8;

    float wev[8], atv[8], xrv[8];
    {
        float4 a = *(const float4*)&We[c0],  b = *(const float4*)&We[c0 + 4];
        wev[0]=a.x; wev[1]=a.y; wev[2]=a.z; wev[3]=a.w;
        wev[4]=b.x; wev[5]=b.y; wev[6]=b.z; wev[7]=b.w;
        float4 c = *(const float4*)&att[c0], d = *(const float4*)&att[c0 + 4];
        atv[0]=c.x; atv[1]=c.y; atv[2]=c.z; atv[3]=c.w;
        atv[4]=d.x; atv[5]=d.y; atv[6]=d.z; atv[7]=d.w;
        float4 p = *(const float4*)&xr[(size_t)n * HCD + c0];
        float4 q = *(const float4*)&xr[(size_t)n * HCD + c0 + 4];
        xrv[0]=p.x; xrv[1]=p.y; xrv[2]=p.z; xrv[3]=p.w;
        xrv[4]=q.x; xrv[5]=q.y; xrv[6]=q.z; xrv[7]=q.w;
    }

    const int s = off[n], e = off[n + 1];
    if (s == e) {
        if (g == 0) {
            float4 z = make_float4(0.f, 0.f, 0.f, 0.f);
            *(float4*)&out_pre[(size_t)n * HCD + c0] = z;
            *(float4*)&out_pre[(size_t)n * HCD + c0 + 4] = z;
        }
        return;
    }

    float mx = -3.0e38f, sm = 0.f;
    float acc[8];
#pragma unroll
    for (int c = 0; c < 8; ++c) acc[c] = 0.f;

    int k = s;
    int2 c2; uint4 xb; bool v;
    {
        int idx = k + g; if (idx > e - 1) idx = e - 1;
        c2 = csr[idx];
        xb = *(const uint4*)&xlbf[(size_t)c2.x * HCD + c0];
        v  = (k + g) < e;
    }

    for (; k < e; k += 4) {
        int2 c2n; uint4 xbn; bool vn;
        {
            int kn = k + 4 + g; int idx = kn; if (idx > e - 1) idx = e - 1;
            c2n = csr[idx];
            xbn = *(const uint4*)&xlbf[(size_t)c2n.x * HCD + c0];
            vn  = kn < e;
        }
        float xv[8];
        xv[0] = __uint_as_float(xb.x << 16);
        xv[1] = __uint_as_float(xb.x & 0xffff0000u);
        xv[2] = __uint_as_float(xb.y << 16);
        xv[3] = __uint_as_float(xb.y & 0xffff0000u);
        xv[4] = __uint_as_float(xb.z << 16);
        xv[5] = __uint_as_float(xb.z & 0xffff0000u);
        xv[6] = __uint_as_float(xb.w << 16);
        xv[7] = __uint_as_float(xb.w & 0xffff0000u);

        float ea = __int_as_float(c2.y);
        float p = 0.f;
#pragma unroll
        for (int c = 0; c < 8; ++c) {
            float m = fmaf(ea, wev[c], xv[c] + xrv[c]);
            m = fmaxf(m, 0.2f * m);                    // leaky_relu slope 0.2
            p = fmaf(m, atv[c], p);
        }
        p += __shfl_xor(p, 1);                          // 4-lane head reduce
        p += __shfl_xor(p, 2);
        if (!v) p = -1.0e30f;

        if (__any(p > mx + 8.f)) {
            float nm = fmaxf(mx, p);
            float sc = __expf(mx - nm);
            sm *= sc;
#pragma unroll
            for (int c = 0; c < 8; ++c) acc[c] *= sc;
            mx = nm;
        }
        float ev = v ? __expf(p - mx) : 0.f;
        sm += ev;
#pragma unroll
        for (int c = 0; c < 8; ++c) acc[c] = fmaf(ev, xv[c], acc[c]);

        c2 = c2n; xb = xbn; v = vn;
    }

    float M = fmaxf(mx, __shfl_xor(mx, 16));
    M = fmaxf(M, __shfl_xor(M, 32));
    float sc = __expf(mx - M);
    float smT = sm * sc;
    smT += __shfl_xor(smT, 16);
    smT += __shfl_xor(smT, 32);
    float inv = 1.f / (smT + 1e-16f);
    float o[8];
#pragma unroll
    for (int c = 0; c < 8; ++c) {
        float a = acc[c] * sc;
        a += __shfl_xor(a, 16);
        a += __shfl_xor(a, 32);
        o[c] = a * inv;
    }
    if (g == 0) {
        *(float4*)&out_pre[(size_t)n * HCD + c0]     = make_float4(o[0], o[1], o[2], o[3]);
        *(float4*)&out_pre[(size_t)n * HCD + c0 + 4] = make_float4(o[4], o[5], o[6], o[7]);
    }
}

// ---------------------------------------------------------------------------
// K6: BN statistics (per-channel sum & sumsq)
// ---------------------------------------------------------------------------
__global__ __launch_bounds__(128) void bnstat_kernel(const float* __restrict__ out_pre,
                                                     float* __restrict__ stats)
{
    const int t = threadIdx.x;
    float s = 0.f, q = 0.f;
    for (int n = blockIdx.x; n < NN; n += gridDim.x) {
        float v = out_pre[n * HCD + t];
        s += v; q += v * v;
    }
    atomicAdd(&stats[t], s);
    atomicAdd(&stats[HCD + t], q);
}

// ---------------------------------------------------------------------------
// K7: normalize + affine + ELU  (float4)
// ---------------------------------------------------------------------------
__global__ __launch_bounds__(256) void bn_elu_kernel(
    const float* __restrict__ out_pre, const float* __restrict__ stats,
    const float* __restrict__ gamma, const float* __restrict__ beta,
    float* __restrict__ out)
{
    int i4 = blockIdx.x * 256 + threadIdx.x;
    if (i4 >= NN * HCD / 4) return;
    int c4 = (i4 & 31) * 4;
    float4 v = *(const float4*)&out_pre[i4 * 4];
    float o[4] = {v.x, v.y, v.z, v.w};
#pragma unroll
    for (int j = 0; j < 4; ++j) {
        int c = c4 + j;
        float mean = stats[c] * (1.f / NN);
        float var  = stats[HCD + c] * (1.f / NN) - mean * mean;
        float inv  = rsqrtf(var + 1e-5f);
        float t = (o[j] - mean) * inv * gamma[c] + beta[c];
        o[j] = (t > 0.f) ? t : expm1f(t);
    }
    *(float4*)&((float*)out)[i4 * 4] = make_float4(o[0], o[1], o[2], o[3]);
}

// ---------------------------------------------------------------------------
extern "C" void kernel_launch(void* const* d_in, const int* in_sizes, int n_in,
                              void* d_out, int out_size, void* d_ws, size_t ws_size,
                              hipStream_t stream)
{
    (void)in_sizes; (void)n_in; (void)out_size; (void)ws_size;
    const float* x    = (const float*)d_in[0];
    const int*   ei   = (const int*)  d_in[1];
    const float* ea   = (const float*)d_in[2];
    const float* Wl   = (const float*)d_in[3];
    const float* bl   = (const float*)d_in[4];
    const float* Wr   = (const float*)d_in[5];
    const float* br   = (const float*)d_in[6];
    const float* We   = (const float*)d_in[7];
    const float* att  = (const float*)d_in[8];
    const float* gamma= (const float*)d_in[10];
    const float* beta = (const float*)d_in[11];
    float* out = (float*)d_out;

    char* wsb = (char*)d_ws;
    size_t o = 0;
    auto take = [&](size_t bytes) -> char* {
        char* p = wsb + o;
        o += (bytes + 255) & ~size_t(255);
        return p;
    };
    unsigned short* xlbf = (unsigned short*)take(sizeof(unsigned short) * NN * HCD);
    float* xr      = (float*)take(sizeof(float) * NN * HCD);
    float* out_pre = (float*)take(sizeof(float) * NN * HCD);
    int2*  csr     = (int2*) take(sizeof(int2)  * NE);
    int*   offs    = (int*)  take(sizeof(int)   * (NN + 1));
    int*   bsum    = (int*)  take(sizeof(int)   * 256);
    int*   boff    = (int*)  take(sizeof(int)   * 256);
    size_t zbytes  = sizeof(int) * NN * 2 + sizeof(float) * 2 * HCD
                   + sizeof(int) * NBKT * 16;
    char*  zbase   = take(zbytes);
    int*   deg     = (int*)zbase;
    int*   cursor  = deg + NN;
    float* stats   = (float*)(cursor + NN);
    int*   gcur    = (int*)(stats + 2 * HCD);

    // staging aliases out_pre (dead until node_kernel; csrfill finishes first)
    int4*  stg     = (int4*)out_pre;

    hipMemsetAsync(zbase, 0, zbytes, stream);

    const int* srcI = ei;
    const int* dstI = ei + NE;

    gemm_mfma<<<dim3((NN + BM - 1) / BM, 2), 256, 49152, stream>>>(
        x, Wl, Wr, bl, br, xlbf, xr);
    bucket_kernel<<<B1B, 256, 0, stream>>>(srcI, dstI, ea, gcur, deg, stg);
    scan1<<<SB, 256, 0, stream>>>(deg, bsum);
    scan2<<<1, 256, 0, stream>>>(bsum, boff);
    scan3<<<SB, 256, 0, stream>>>(deg, boff, offs);
    csrfill_kernel<<<256, 256, 0, stream>>>(stg, gcur, offs, cursor, csr);
    node_kernel<<<(NN + 3) / 4, 256, 0, stream>>>(xlbf, xr, We, att, offs, csr, out_pre);
    bnstat_kernel<<<512, 128, 0, stream>>>(out_pre, stats);
    bn_elu_kernel<<<(NN * HCD / 4 + 255) / 256, 256, 0, stream>>>(out_pre, stats,
                                                                  gamma, beta, out);
}